// Round 7
// baseline (7776.806 us; speedup 1.0000x reference)
//
#include <hip/hip_runtime.h>
#include <math.h>

constexpr int Bn = 64;
constexpr int Tn = 512;
constexpr int Hn = 768;
constexpr int RTn = Bn * Tn;               // 32768 rows

constexpr int NPROD = 24;                  // col-blocks per group
constexpr int NGRP  = 8;                   // batch groups (8 batches each)
constexpr int SLOTS = 4;                   // publish ring depth
constexpr int GSTR  = NPROD * 512;         // floats per group per slot
constexpr int SSTR  = NGRP * GSTR;         // floats per slot
constexpr int FSTR  = 32;                  // flag stride (ints) = 128B line
constexpr int ROWF  = 772;                 // LDS row stride (768 + 4 pad)

// workspace offsets (in floats)
constexpr size_t OFF_XP    = 0;
constexpr size_t OFF_H12   = OFF_XP  + (size_t)RTn * Hn;
constexpr size_t OFF_TAGX  = OFF_H12 + (size_t)RTn * Hn;
constexpr size_t OFF_C12   = OFF_TAGX + (size_t)RTn;
constexpr size_t OFF_PUB   = OFF_C12  + Hn;
constexpr size_t OFF_FLAGS = OFF_PUB  + (size_t)SLOTS * SSTR;  // int region

// ---------------------------------------------------------------------------
__global__ void __launch_bounds__(256) c12_kernel(const float* __restrict__ Whh12,
                                                  const float* __restrict__ hinit,
                                                  const float* __restrict__ b12,
                                                  float* __restrict__ c12) {
    int j = blockIdx.x * 256 + threadIdx.x;
    if (j >= Hn) return;
    float s = b12[j];
    const float* row = Whh12 + (size_t)j * Hn;
    for (int e = 0; e < Hn; ++e) s += row[e] * hinit[e];
    c12[j] = s;
}

// ---------------------------------------------------------------------------
__global__ void __launch_bounds__(256) tagx_kernel(const float* __restrict__ bert,
                                                   const float* __restrict__ Wtag,
                                                   const float* __restrict__ btag,
                                                   float* __restrict__ tagx) {
    int r = blockIdx.x * 4 + (threadIdx.x >> 6);
    int lane = threadIdx.x & 63;
    const float* wx = Wtag + 2 * Hn;
    const float* row = bert + (size_t)r * Hn;
    float s = 0.f;
    for (int e = lane; e < Hn; e += 64) s += row[e] * wx[e];
    #pragma unroll
    for (int m = 1; m < 64; m <<= 1) s += __shfl_xor(s, m, 64);
    if (lane == 0) tagx[r] = s + btag[0];
}

// ---------------------------------------------------------------------------
// Precompute GEMM (fp32): xp11 and tanh'ed h12_seq.
__global__ void __launch_bounds__(256) gemm_pre(const float* __restrict__ bert,
                                                const float* __restrict__ Wih11,
                                                const float* __restrict__ Wih12,
                                                const float* __restrict__ b11,
                                                const float* __restrict__ c12,
                                                float* __restrict__ xp,
                                                float* __restrict__ h12) {
    constexpr int BM = 128, BN = 64, BK = 16;
    __shared__ float As[BK][BM];
    __shared__ float Ws[BK][BN];
    const int bid = blockIdx.x;
    const int mt = bid / 24, nt = bid % 24;
    const int r0 = mt * BM;
    const int n0 = nt * BN;
    const bool second = (n0 >= Hn);
    const float* W = second ? Wih12 : Wih11;
    const int jbase = second ? (n0 - Hn) : n0;
    const int tid = threadIdx.x;
    const int ty = tid >> 4, tx = tid & 15;
    const int lrow = tid >> 1, lhalf = (tid & 1) * 8;
    const int wjl = tid & 63, wkk = tid >> 6;
    float acc[8][4] = {};
    for (int e0 = 0; e0 < Hn; e0 += BK) {
        float4 av0 = *(const float4*)(bert + (size_t)(r0 + lrow) * Hn + e0 + lhalf);
        float4 av1 = *(const float4*)(bert + (size_t)(r0 + lrow) * Hn + e0 + lhalf + 4);
        float4 wv  = *(const float4*)(W + (size_t)(jbase + wjl) * Hn + e0 + wkk * 4);
        As[lhalf + 0][lrow] = av0.x; As[lhalf + 1][lrow] = av0.y;
        As[lhalf + 2][lrow] = av0.z; As[lhalf + 3][lrow] = av0.w;
        As[lhalf + 4][lrow] = av1.x; As[lhalf + 5][lrow] = av1.y;
        As[lhalf + 6][lrow] = av1.z; As[lhalf + 7][lrow] = av1.w;
        Ws[wkk * 4 + 0][wjl] = wv.x; Ws[wkk * 4 + 1][wjl] = wv.y;
        Ws[wkk * 4 + 2][wjl] = wv.z; Ws[wkk * 4 + 3][wjl] = wv.w;
        __syncthreads();
        #pragma unroll
        for (int k = 0; k < BK; ++k) {
            float a[8], w[4];
            *(float4*)&a[0] = *(const float4*)&As[k][ty * 8];
            *(float4*)&a[4] = *(const float4*)&As[k][ty * 8 + 4];
            *(float4*)&w[0] = *(const float4*)&Ws[k][tx * 4];
            #pragma unroll
            for (int ii = 0; ii < 8; ++ii)
                #pragma unroll
                for (int jj = 0; jj < 4; ++jj)
                    acc[ii][jj] += a[ii] * w[jj];
        }
        __syncthreads();
    }
    #pragma unroll
    for (int ii = 0; ii < 8; ++ii) {
        size_t r = (size_t)(r0 + ty * 8 + ii);
        if (!second) {
            #pragma unroll
            for (int jj = 0; jj < 4; ++jj) {
                int n = n0 + tx * 4 + jj;
                xp[r * Hn + n] = acc[ii][jj] + b11[n];
            }
        } else {
            #pragma unroll
            for (int jj = 0; jj < 4; ++jj) {
                int n = n0 - Hn + tx * 4 + jj;
                h12[r * Hn + n] = tanhf(acc[ii][jj] + c12[n]);
            }
        }
    }
}

// ---------------------------------------------------------------------------
// Dataflow scan v3: 192 blocks = 8 groups(8 batches) x 24 col-blocks(32 cols),
// 1024 threads (16 waves). Arrival-driven exchange: wave w polls producer w's
// flag (lane-0 spin) and gathers its 2KB slice immediately; waves 0-7 then
// handle producer 16+w. Publish = relaxed agent-scope stores, drained by
// barrier D; flag next; output HBM stores AFTER the flag (off critical chain).
__global__ void __launch_bounds__(1024, 1) scan_kernel(
        const float* __restrict__ xp, const float* __restrict__ h12,
        const float* __restrict__ tagx,
        const float* __restrict__ Whh11, const float* __restrict__ Wih21,
        const float* __restrict__ Whh21, const float* __restrict__ b21,
        const float* __restrict__ Wtag,
        float* __restrict__ pub, int* __restrict__ flags,
        float* __restrict__ out) {
    __shared__ float h1s[8 * ROWF];          // 24.7 KB
    __shared__ float h2s[8 * ROWF];
    __shared__ float wt1[Hn], wt2[Hn];       // 6 KB
    __shared__ float redbuf[16][8][2][32];   // 32 KB [wave][batch][acc][j]
    __shared__ float tagbuf[8];

    const int tid  = threadIdx.x;
    const int wv   = tid >> 6;          // wave 0..15
    const int lane = tid & 63;
    const int bid  = blockIdx.x;
    const int g    = bid & 7;           // group (XCD round-robin heuristic)
    const int prod = bid >> 3;          // col-block 0..23
    const int j    = tid & 31;          // col-local 0..31
    const int ks   = tid >> 5;          // k-slice 0..31 -> k in [ks*24, ks*24+24)
    const int col  = prod * 32 + j;

    // loop-invariant weights: 18 float4 = 72 VGPR
    float4 w11r[6], w21r[6], w2hr[6];
    {
        const float* p1 = Whh11 + (size_t)col * Hn + ks * 24;
        const float* p2 = Wih21 + (size_t)col * Hn + ks * 24;
        const float* p3 = Whh21 + (size_t)col * Hn + ks * 24;
        #pragma unroll
        for (int q = 0; q < 6; ++q) {
            w11r[q] = *(const float4*)(p1 + q * 4);
            w21r[q] = *(const float4*)(p2 + q * 4);
            w2hr[q] = *(const float4*)(p3 + q * 4);
        }
    }
    for (int i = tid; i < Hn; i += 1024) { wt1[i] = Wtag[i]; wt2[i] = Wtag[Hn + i]; }
    const float bias21 = b21[col];

    float* outO   = out;
    float* outH2  = out + RTn;
    float* outTag = out + RTn + (size_t)RTn * Hn;
    int* myflag = flags + (g * NPROD + prod) * FSTR;

    // gather addressing (t-invariant): lane covers 8 floats of a 512-float slice
    const int gm  = (lane & 31) >> 2;            // batch row 0..7
    const int gc  = (lane & 3) * 8;              // col offset 0..24
    float* const gdst0 = ((lane < 32) ? h1s : h2s) + gm * ROWF + gc;

    for (int t = 0; t < Tn; ++t) {
        // flag-independent prefetch (before any waiting)
        float xpv = 0.f, h12pv = 0.f, tgxv = 0.f;
        if (tid < 256) {
            int m = tid >> 5;
            size_t rr = (size_t)(g * 8 + m) * Tn + t;
            xpv   = xp  [rr * Hn + col];
            h12pv = h12 [rr * Hn + col];
            tgxv  = tagx[rr];
        }

        // arrival-driven poll + gather (no barrier A needed: prev-step LDS
        // reads all completed before last step's barrier D)
        {
            const float* pubc = pub + (size_t)(t & 3) * SSTR + g * GSTR;
            const int np = (wv < 8) ? 2 : 1;
            #pragma unroll
            for (int pi = 0; pi < 2; ++pi) {
                if (pi < np) {
                    const int p = (pi == 0) ? wv : (16 + wv);
                    if (lane == 0) {
                        const int* f = flags + (g * NPROD + p) * FSTR;
                        while (__hip_atomic_load(f, __ATOMIC_RELAXED,
                                                 __HIP_MEMORY_SCOPE_AGENT) < t)
                            __builtin_amdgcn_s_sleep(1);
                    }
                    // wave reconverges here; gather p's 2KB slice
                    const float* src = pubc + p * 512 + lane * 8;
                    float v[8];
                    #pragma unroll
                    for (int i = 0; i < 8; ++i)
                        v[i] = __hip_atomic_load(src + i, __ATOMIC_RELAXED,
                                                 __HIP_MEMORY_SCOPE_AGENT);
                    float* dst = gdst0 + p * 32;
                    #pragma unroll
                    for (int i = 0; i < 8; ++i) dst[i] = v[i];
                }
            }
        }
        __syncthreads();   // B: full state staged

        // gate: wave wv<8 handles batch wv; lane covers k = lane*12..+12
        if (wv < 8) {
            const int k0 = lane * 12;
            float s0 = 0.f, s1 = 0.f, s2 = 0.f, s3 = 0.f;
            #pragma unroll
            for (int q = 0; q < 3; ++q) {
                float4 x1 = *(const float4*)&h1s[wv * ROWF + k0 + q * 4];
                float4 x2 = *(const float4*)&h2s[wv * ROWF + k0 + q * 4];
                float4 u1 = *(const float4*)&wt1[k0 + q * 4];
                float4 u2 = *(const float4*)&wt2[k0 + q * 4];
                s0 = fmaf(x1.x, u1.x, s0); s1 = fmaf(x1.y, u1.y, s1);
                s2 = fmaf(x1.z, u1.z, s2); s3 = fmaf(x1.w, u1.w, s3);
                s0 = fmaf(x2.x, u2.x, s0); s1 = fmaf(x2.y, u2.y, s1);
                s2 = fmaf(x2.z, u2.z, s2); s3 = fmaf(x2.w, u2.w, s3);
            }
            float s = (s0 + s1) + (s2 + s3);
            #pragma unroll
            for (int mm = 1; mm < 64; mm <<= 1) s += __shfl_xor(s, mm, 64);
            if (lane == 0) tagbuf[wv] = s;
        }

        // matvec partials: 8 batches, 24-k slice per thread, register weights
        #pragma unroll 4
        for (int b = 0; b < 8; ++b) {
            const float* r1 = &h1s[b * ROWF + ks * 24];
            const float* r2 = &h2s[b * ROWF + ks * 24];
            float a0 = 0.f, a1 = 0.f, a2 = 0.f, a3 = 0.f;
            float c0 = 0.f, c1 = 0.f, c2 = 0.f, c3 = 0.f;
            float d0 = 0.f, d1 = 0.f, d2 = 0.f, d3 = 0.f;
            #pragma unroll
            for (int q = 0; q < 6; ++q) {
                float4 x1 = *(const float4*)(r1 + q * 4);
                float4 x2 = *(const float4*)(r2 + q * 4);
                a0 = fmaf(x1.x, w11r[q].x, a0); a1 = fmaf(x1.y, w11r[q].y, a1);
                a2 = fmaf(x1.z, w11r[q].z, a2); a3 = fmaf(x1.w, w11r[q].w, a3);
                c0 = fmaf(x1.x, w21r[q].x, c0); c1 = fmaf(x1.y, w21r[q].y, c1);
                c2 = fmaf(x1.z, w21r[q].z, c2); c3 = fmaf(x1.w, w21r[q].w, c3);
                d0 = fmaf(x2.x, w2hr[q].x, d0); d1 = fmaf(x2.y, w2hr[q].y, d1);
                d2 = fmaf(x2.z, w2hr[q].z, d2); d3 = fmaf(x2.w, w2hr[q].w, d3);
            }
            float a11 = (a0 + a1) + (a2 + a3);
            float a21 = ((c0 + c1) + (c2 + c3)) + ((d0 + d1) + (d2 + d3));
            a11 += __shfl_xor(a11, 32, 64);   // combine the wave's two k-slices
            a21 += __shfl_xor(a21, 32, 64);
            if (lane < 32) {
                redbuf[wv][b][0][lane] = a11;
                redbuf[wv][b][1][lane] = a21;
            }
        }
        __syncthreads();   // C: redbuf + tagbuf ready

        // epilogue: 256 threads = (batch m, col jc); publish first
        float o = 0.f, tg = 0.f, h2nv = 0.f;
        if (tid < 256) {
            int m = tid >> 5, jc = tid & 31;
            float f11 = 0.f, f21 = 0.f;
            #pragma unroll
            for (int w = 0; w < 16; ++w) {
                f11 += redbuf[w][m][0][jc];
                f21 += redbuf[w][m][1][jc];
            }
            tg = tagbuf[m] + tgxv;
            o  = 1.f / (1.f + expf(-tg));
            float h11v = tanhf(xpv + f11);
            float h21v = tanhf(f21 + bias21);
            float h2pv = h2s[m * ROWF + prod * 32 + jc];
            float h1nv = h11v * (1.f - o) + h12pv * o;
            h2nv = h2pv * (1.f - o) + h21v * o;
            float* pn = pub + (size_t)((t + 1) & 3) * SSTR + g * GSTR + prod * 512;
            __hip_atomic_store(pn + m * 32 + jc, h1nv,
                               __ATOMIC_RELAXED, __HIP_MEMORY_SCOPE_AGENT);
            __hip_atomic_store(pn + 256 + m * 32 + jc, h2nv,
                               __ATOMIC_RELAXED, __HIP_MEMORY_SCOPE_AGENT);
        }
        __syncthreads();   // D: vmcnt(0) drains the publish stores
        if (tid == 0)
            __hip_atomic_store(myflag, t + 1, __ATOMIC_RELAXED,
                               __HIP_MEMORY_SCOPE_AGENT);
        // output stores AFTER the flag — off the inter-block critical chain
        if (tid < 256) {
            int m = tid >> 5, jc = tid & 31;
            size_t rr = (size_t)(g * 8 + m) * Tn + t;
            outH2[rr * Hn + col] = h2nv;
            if (jc == 0 && prod == 0) { outO[rr] = o; outTag[rr] = tg; }
        }
    }
}

// ---------------------------------------------------------------------------
extern "C" void kernel_launch(void* const* d_in, const int* in_sizes, int n_in,
                              void* d_out, int out_size, void* d_ws, size_t ws_size,
                              hipStream_t stream) {
    const float* bert  = (const float*)d_in[0];
    const float* Wih11 = (const float*)d_in[1];
    const float* Whh11 = (const float*)d_in[2];
    const float* b11   = (const float*)d_in[3];
    const float* Wih12 = (const float*)d_in[4];
    const float* Whh12 = (const float*)d_in[5];
    const float* b12   = (const float*)d_in[6];
    const float* Wih21 = (const float*)d_in[7];
    const float* Whh21 = (const float*)d_in[8];
    const float* b21   = (const float*)d_in[9];
    const float* Wtag  = (const float*)d_in[10];
    const float* btag  = (const float*)d_in[11];
    const float* hinit = (const float*)d_in[12];
    float* ws = (float*)d_ws;
    float* xp    = ws + OFF_XP;
    float* h12   = ws + OFF_H12;
    float* tagx  = ws + OFF_TAGX;
    float* c12   = ws + OFF_C12;
    float* pub   = ws + OFF_PUB;
    int*   flags = (int*)(ws + OFF_FLAGS);
    float* out   = (float*)d_out;

    // zero publish ring (slot 0 = initial h=0 state) and flags
    hipMemsetAsync(pub,   0, (size_t)SLOTS * SSTR * sizeof(float), stream);
    hipMemsetAsync(flags, 0, NGRP * NPROD * FSTR * sizeof(int), stream);

    c12_kernel<<<3, 256, 0, stream>>>(Whh12, hinit, b12, c12);
    gemm_pre<<<256 * 24, 256, 0, stream>>>(bert, Wih11, Wih12, b11, c12, xp, h12);
    tagx_kernel<<<RTn / 4, 256, 0, stream>>>(bert, Wtag, btag, tagx);

    void* params[] = { &xp, &h12, &tagx, &Whh11, &Wih21, &Whh21, &b21, &Wtag,
                       &pub, &flags, &out };
    hipLaunchCooperativeKernel((void*)scan_kernel, dim3(192), dim3(1024),
                               params, 0, stream);
}

// Round 8
// 4996.640 us; speedup vs baseline: 1.5564x; 1.5564x over previous
//
#include <hip/hip_runtime.h>
#include <math.h>

constexpr int Bn = 64;
constexpr int Tn = 512;
constexpr int Hn = 768;
constexpr int RTn = Bn * Tn;               // 32768 rows

constexpr int NPROD = 24;                  // col-blocks per group
constexpr int NGRP  = 8;                   // batch groups (8 batches each)
constexpr int SLOTS = 4;                   // publish ring depth
constexpr int GSTR  = NPROD * 512;         // floats per group per slot
constexpr int SSTR  = NGRP * GSTR;         // floats per slot
constexpr int FSTR  = 32;                  // flag stride (ints) = 128B line
constexpr int ROWF  = 772;                 // LDS row stride (768 + 4 pad)

// workspace offsets (in floats)
constexpr size_t OFF_XP    = 0;
constexpr size_t OFF_H12   = OFF_XP  + (size_t)RTn * Hn;
constexpr size_t OFF_TAGX  = OFF_H12 + (size_t)RTn * Hn;
constexpr size_t OFF_C12   = OFF_TAGX + (size_t)RTn;
constexpr size_t OFF_PUB   = OFF_C12  + Hn;
constexpr size_t OFF_FLAGS = OFF_PUB  + (size_t)SLOTS * SSTR;  // int region

// ---------------------------------------------------------------------------
__global__ void __launch_bounds__(256) c12_kernel(const float* __restrict__ Whh12,
                                                  const float* __restrict__ hinit,
                                                  const float* __restrict__ b12,
                                                  float* __restrict__ c12) {
    int j = blockIdx.x * 256 + threadIdx.x;
    if (j >= Hn) return;
    float s = b12[j];
    const float* row = Whh12 + (size_t)j * Hn;
    for (int e = 0; e < Hn; ++e) s += row[e] * hinit[e];
    c12[j] = s;
}

// ---------------------------------------------------------------------------
__global__ void __launch_bounds__(256) tagx_kernel(const float* __restrict__ bert,
                                                   const float* __restrict__ Wtag,
                                                   const float* __restrict__ btag,
                                                   float* __restrict__ tagx) {
    int r = blockIdx.x * 4 + (threadIdx.x >> 6);
    int lane = threadIdx.x & 63;
    const float* wx = Wtag + 2 * Hn;
    const float* row = bert + (size_t)r * Hn;
    float s = 0.f;
    for (int e = lane; e < Hn; e += 64) s += row[e] * wx[e];
    #pragma unroll
    for (int m = 1; m < 64; m <<= 1) s += __shfl_xor(s, m, 64);
    if (lane == 0) tagx[r] = s + btag[0];
}

// ---------------------------------------------------------------------------
// Precompute GEMM (fp32): xp11 and tanh'ed h12_seq.
__global__ void __launch_bounds__(256) gemm_pre(const float* __restrict__ bert,
                                                const float* __restrict__ Wih11,
                                                const float* __restrict__ Wih12,
                                                const float* __restrict__ b11,
                                                const float* __restrict__ c12,
                                                float* __restrict__ xp,
                                                float* __restrict__ h12) {
    constexpr int BM = 128, BN = 64, BK = 16;
    __shared__ float As[BK][BM];
    __shared__ float Ws[BK][BN];
    const int bid = blockIdx.x;
    const int mt = bid / 24, nt = bid % 24;
    const int r0 = mt * BM;
    const int n0 = nt * BN;
    const bool second = (n0 >= Hn);
    const float* W = second ? Wih12 : Wih11;
    const int jbase = second ? (n0 - Hn) : n0;
    const int tid = threadIdx.x;
    const int ty = tid >> 4, tx = tid & 15;
    const int lrow = tid >> 1, lhalf = (tid & 1) * 8;
    const int wjl = tid & 63, wkk = tid >> 6;
    float acc[8][4] = {};
    for (int e0 = 0; e0 < Hn; e0 += BK) {
        float4 av0 = *(const float4*)(bert + (size_t)(r0 + lrow) * Hn + e0 + lhalf);
        float4 av1 = *(const float4*)(bert + (size_t)(r0 + lrow) * Hn + e0 + lhalf + 4);
        float4 wv  = *(const float4*)(W + (size_t)(jbase + wjl) * Hn + e0 + wkk * 4);
        As[lhalf + 0][lrow] = av0.x; As[lhalf + 1][lrow] = av0.y;
        As[lhalf + 2][lrow] = av0.z; As[lhalf + 3][lrow] = av0.w;
        As[lhalf + 4][lrow] = av1.x; As[lhalf + 5][lrow] = av1.y;
        As[lhalf + 6][lrow] = av1.z; As[lhalf + 7][lrow] = av1.w;
        Ws[wkk * 4 + 0][wjl] = wv.x; Ws[wkk * 4 + 1][wjl] = wv.y;
        Ws[wkk * 4 + 2][wjl] = wv.z; Ws[wkk * 4 + 3][wjl] = wv.w;
        __syncthreads();
        #pragma unroll
        for (int k = 0; k < BK; ++k) {
            float a[8], w[4];
            *(float4*)&a[0] = *(const float4*)&As[k][ty * 8];
            *(float4*)&a[4] = *(const float4*)&As[k][ty * 8 + 4];
            *(float4*)&w[0] = *(const float4*)&Ws[k][tx * 4];
            #pragma unroll
            for (int ii = 0; ii < 8; ++ii)
                #pragma unroll
                for (int jj = 0; jj < 4; ++jj)
                    acc[ii][jj] += a[ii] * w[jj];
        }
        __syncthreads();
    }
    #pragma unroll
    for (int ii = 0; ii < 8; ++ii) {
        size_t r = (size_t)(r0 + ty * 8 + ii);
        if (!second) {
            #pragma unroll
            for (int jj = 0; jj < 4; ++jj) {
                int n = n0 + tx * 4 + jj;
                xp[r * Hn + n] = acc[ii][jj] + b11[n];
            }
        } else {
            #pragma unroll
            for (int jj = 0; jj < 4; ++jj) {
                int n = n0 - Hn + tx * 4 + jj;
                h12[r * Hn + n] = tanhf(acc[ii][jj] + c12[n]);
            }
        }
    }
}

// ---------------------------------------------------------------------------
// Dataflow scan v4 (= R6 exchange + pinned register weights, 512 threads).
// 192 blocks = 8 groups(8 batches) x 24 col-blocks(32 cols), 8 waves.
// Thread (j=tid&31, ks=tid>>5) holds W[col][ks*48..+48) for 3 matrices in
// 36 float4 = 144 VGPRs, PINNED via asm so the compiler cannot rematerialize
// them from L2 each step. Bulk spin (24 pollers) -> bulk gather (MLP).
// Output HBM stores after the flag (off the inter-block critical chain).
__global__ void __launch_bounds__(512, 2) scan_kernel(
        const float* __restrict__ xp, const float* __restrict__ h12,
        const float* __restrict__ tagx,
        const float* __restrict__ Whh11, const float* __restrict__ Wih21,
        const float* __restrict__ Whh21, const float* __restrict__ b21,
        const float* __restrict__ Wtag,
        float* __restrict__ pub, int* __restrict__ flags,
        float* __restrict__ out) {
    __shared__ float h1s[8 * ROWF];          // 24.7 KB
    __shared__ float h2s[8 * ROWF];
    __shared__ float wt1[Hn], wt2[Hn];       // 6 KB
    __shared__ float redbuf[8][8][2][32];    // 16 KB [wave][batch][acc][j]
    __shared__ float tagbuf[8];

    const int tid  = threadIdx.x;
    const int wv   = tid >> 6;          // wave 0..7
    const int lane = tid & 63;
    const int bid  = blockIdx.x;
    const int g    = bid & 7;           // group (XCD round-robin heuristic)
    const int prod = bid >> 3;          // col-block 0..23
    const int j    = tid & 31;          // col-local 0..31
    const int ks   = tid >> 5;          // k-slice 0..15 -> k in [ks*48, ks*48+48)
    const int col  = prod * 32 + j;

    // loop-invariant weights: 36 float4 = 144 VGPR, pinned
    float4 w11r[12], w21r[12], w2hr[12];
    {
        const float* p1 = Whh11 + (size_t)col * Hn + ks * 48;
        const float* p2 = Wih21 + (size_t)col * Hn + ks * 48;
        const float* p3 = Whh21 + (size_t)col * Hn + ks * 48;
        #pragma unroll
        for (int q = 0; q < 12; ++q) {
            w11r[q] = *(const float4*)(p1 + q * 4);
            w21r[q] = *(const float4*)(p2 + q * 4);
            w2hr[q] = *(const float4*)(p3 + q * 4);
        }
        #pragma unroll
        for (int q = 0; q < 12; ++q) {
            asm volatile("" : "+v"(w11r[q].x), "+v"(w11r[q].y),
                              "+v"(w11r[q].z), "+v"(w11r[q].w));
            asm volatile("" : "+v"(w21r[q].x), "+v"(w21r[q].y),
                              "+v"(w21r[q].z), "+v"(w21r[q].w));
            asm volatile("" : "+v"(w2hr[q].x), "+v"(w2hr[q].y),
                              "+v"(w2hr[q].z), "+v"(w2hr[q].w));
        }
    }
    for (int i = tid; i < Hn; i += 512) { wt1[i] = Wtag[i]; wt2[i] = Wtag[Hn + i]; }
    const float bias21 = b21[col];

    float* outO   = out;
    float* outH2  = out + RTn;
    float* outTag = out + RTn + (size_t)RTn * Hn;
    int* myflag = flags + (g * NPROD + prod) * FSTR;

    for (int t = 0; t < Tn; ++t) {
        // flag-independent prefetch (before the spin)
        float xpv = 0.f, h12pv = 0.f, tgxv = 0.f;
        if (tid < 256) {
            int m = tid >> 5;
            size_t rr = (size_t)(g * 8 + m) * Tn + t;
            xpv   = xp  [rr * Hn + col];
            h12pv = h12 [rr * Hn + col];
            tgxv  = tagx[rr];
        }

        // spin: 24 parallel pollers, one per producer flag
        if (tid < NPROD) {
            const int* f = flags + (g * NPROD + tid) * FSTR;
            while (__hip_atomic_load(f, __ATOMIC_RELAXED,
                                     __HIP_MEMORY_SCOPE_AGENT) < t)
                __builtin_amdgcn_s_sleep(2);
        }
        __syncthreads();   // A: all producers ready; prev-step LDS reads done

        // bulk gather 48 KB (coherent loads), issue-all-then-write, 2 batches
        {
            const float* pubc = pub + (size_t)(t & 3) * SSTR + g * GSTR;
            #pragma unroll
            for (int h = 0; h < 2; ++h) {
                float tmp[12];
                #pragma unroll
                for (int i = 0; i < 12; ++i) {
                    int idx = tid + (h * 12 + i) * 512;
                    int p = idx >> 9, rem = idx & 511;
                    int a = rem >> 8, b = (rem >> 5) & 7, c = rem & 31;
                    tmp[i] = __hip_atomic_load(
                        pubc + p * 512 + a * 256 + b * 32 + c,
                        __ATOMIC_RELAXED, __HIP_MEMORY_SCOPE_AGENT);
                }
                #pragma unroll
                for (int i = 0; i < 12; ++i) {
                    int idx = tid + (h * 12 + i) * 512;
                    int p = idx >> 9, rem = idx & 511;
                    int a = rem >> 8, b = (rem >> 5) & 7, c = rem & 31;
                    float* dst = a ? h2s : h1s;
                    dst[b * ROWF + p * 32 + c] = tmp[i];
                }
            }
        }
        __syncthreads();   // B: state staged

        // gate: wave wv handles batch wv; lane covers k = lane*12..+12
        {
            const int k0 = lane * 12;
            float s0 = 0.f, s1 = 0.f, s2 = 0.f, s3 = 0.f;
            #pragma unroll
            for (int q = 0; q < 3; ++q) {
                float4 x1 = *(const float4*)&h1s[wv * ROWF + k0 + q * 4];
                float4 x2 = *(const float4*)&h2s[wv * ROWF + k0 + q * 4];
                float4 u1 = *(const float4*)&wt1[k0 + q * 4];
                float4 u2 = *(const float4*)&wt2[k0 + q * 4];
                s0 = fmaf(x1.x, u1.x, s0); s1 = fmaf(x1.y, u1.y, s1);
                s2 = fmaf(x1.z, u1.z, s2); s3 = fmaf(x1.w, u1.w, s3);
                s0 = fmaf(x2.x, u2.x, s0); s1 = fmaf(x2.y, u2.y, s1);
                s2 = fmaf(x2.z, u2.z, s2); s3 = fmaf(x2.w, u2.w, s3);
            }
            float s = (s0 + s1) + (s2 + s3);
            #pragma unroll
            for (int mm = 1; mm < 64; mm <<= 1) s += __shfl_xor(s, mm, 64);
            if (lane == 0) tagbuf[wv] = s;
        }

        // matvec partials: 8 batches, 48-k slice per thread, pinned weights
        #pragma unroll 2
        for (int b = 0; b < 8; ++b) {
            const float* r1 = &h1s[b * ROWF + ks * 48];
            const float* r2 = &h2s[b * ROWF + ks * 48];
            float a0 = 0.f, a1 = 0.f, a2 = 0.f, a3 = 0.f;
            float c0 = 0.f, c1 = 0.f, c2 = 0.f, c3 = 0.f;
            float d0 = 0.f, d1 = 0.f, d2 = 0.f, d3 = 0.f;
            #pragma unroll
            for (int q = 0; q < 12; ++q) {
                float4 x1 = *(const float4*)(r1 + q * 4);
                float4 x2 = *(const float4*)(r2 + q * 4);
                a0 = fmaf(x1.x, w11r[q].x, a0); a1 = fmaf(x1.y, w11r[q].y, a1);
                a2 = fmaf(x1.z, w11r[q].z, a2); a3 = fmaf(x1.w, w11r[q].w, a3);
                c0 = fmaf(x1.x, w21r[q].x, c0); c1 = fmaf(x1.y, w21r[q].y, c1);
                c2 = fmaf(x1.z, w21r[q].z, c2); c3 = fmaf(x1.w, w21r[q].w, c3);
                d0 = fmaf(x2.x, w2hr[q].x, d0); d1 = fmaf(x2.y, w2hr[q].y, d1);
                d2 = fmaf(x2.z, w2hr[q].z, d2); d3 = fmaf(x2.w, w2hr[q].w, d3);
            }
            float a11 = (a0 + a1) + (a2 + a3);
            float a21 = ((c0 + c1) + (c2 + c3)) + ((d0 + d1) + (d2 + d3));
            a11 += __shfl_xor(a11, 32, 64);   // combine the wave's two k-slices
            a21 += __shfl_xor(a21, 32, 64);
            if (lane < 32) {
                redbuf[wv][b][0][lane] = a11;
                redbuf[wv][b][1][lane] = a21;
            }
        }
        __syncthreads();   // C: redbuf + tagbuf ready

        // epilogue: 256 threads = (batch m, col jc); publish first
        float o = 0.f, tg = 0.f, h2nv = 0.f;
        if (tid < 256) {
            int m = tid >> 5, jc = tid & 31;
            float f11 = 0.f, f21 = 0.f;
            #pragma unroll
            for (int w = 0; w < 8; ++w) {
                f11 += redbuf[w][m][0][jc];
                f21 += redbuf[w][m][1][jc];
            }
            tg = tagbuf[m] + tgxv;
            o  = 1.f / (1.f + expf(-tg));
            float h11v = tanhf(xpv + f11);
            float h21v = tanhf(f21 + bias21);
            float h2pv = h2s[m * ROWF + prod * 32 + jc];
            float h1nv = h11v * (1.f - o) + h12pv * o;
            h2nv = h2pv * (1.f - o) + h21v * o;
            float* pn = pub + (size_t)((t + 1) & 3) * SSTR + g * GSTR + prod * 512;
            __hip_atomic_store(pn + m * 32 + jc, h1nv,
                               __ATOMIC_RELAXED, __HIP_MEMORY_SCOPE_AGENT);
            __hip_atomic_store(pn + 256 + m * 32 + jc, h2nv,
                               __ATOMIC_RELAXED, __HIP_MEMORY_SCOPE_AGENT);
        }
        __syncthreads();   // D: vmcnt(0) drains the publish stores
        if (tid == 0)
            __hip_atomic_store(myflag, t + 1, __ATOMIC_RELAXED,
                               __HIP_MEMORY_SCOPE_AGENT);
        // output stores AFTER the flag — off the inter-block critical chain
        if (tid < 256) {
            int m = tid >> 5, jc = tid & 31;
            size_t rr = (size_t)(g * 8 + m) * Tn + t;
            outH2[rr * Hn + col] = h2nv;
            if (jc == 0 && prod == 0) { outO[rr] = o; outTag[rr] = tg; }
        }
    }
}

// ---------------------------------------------------------------------------
extern "C" void kernel_launch(void* const* d_in, const int* in_sizes, int n_in,
                              void* d_out, int out_size, void* d_ws, size_t ws_size,
                              hipStream_t stream) {
    const float* bert  = (const float*)d_in[0];
    const float* Wih11 = (const float*)d_in[1];
    const float* Whh11 = (const float*)d_in[2];
    const float* b11   = (const float*)d_in[3];
    const float* Wih12 = (const float*)d_in[4];
    const float* Whh12 = (const float*)d_in[5];
    const float* b12   = (const float*)d_in[6];
    const float* Wih21 = (const float*)d_in[7];
    const float* Whh21 = (const float*)d_in[8];
    const float* b21   = (const float*)d_in[9];
    const float* Wtag  = (const float*)d_in[10];
    const float* btag  = (const float*)d_in[11];
    const float* hinit = (const float*)d_in[12];
    float* ws = (float*)d_ws;
    float* xp    = ws + OFF_XP;
    float* h12   = ws + OFF_H12;
    float* tagx  = ws + OFF_TAGX;
    float* c12   = ws + OFF_C12;
    float* pub   = ws + OFF_PUB;
    int*   flags = (int*)(ws + OFF_FLAGS);
    float* out   = (float*)d_out;

    // zero publish ring (slot 0 = initial h=0 state) and flags
    hipMemsetAsync(pub,   0, (size_t)SLOTS * SSTR * sizeof(float), stream);
    hipMemsetAsync(flags, 0, NGRP * NPROD * FSTR * sizeof(int), stream);

    c12_kernel<<<3, 256, 0, stream>>>(Whh12, hinit, b12, c12);
    gemm_pre<<<256 * 24, 256, 0, stream>>>(bert, Wih11, Wih12, b11, c12, xp, h12);
    tagx_kernel<<<RTn / 4, 256, 0, stream>>>(bert, Wtag, btag, tagx);

    void* params[] = { &xp, &h12, &tagx, &Whh11, &Wih21, &Whh21, &b21, &Wtag,
                       &pub, &flags, &out };
    hipLaunchCooperativeKernel((void*)scan_kernel, dim3(192), dim3(512),
                               params, 0, stream);
}

// Round 9
// 3271.930 us; speedup vs baseline: 2.3768x; 1.5271x over previous
//
#include <hip/hip_runtime.h>
#include <math.h>

typedef __attribute__((ext_vector_type(8))) short short8v;   // 8 bf16
typedef __attribute__((ext_vector_type(4))) float f32x4;     // 4 f32 acc

constexpr int Bn = 64;
constexpr int Tn = 512;
constexpr int Hn = 768;
constexpr int RTn = Bn * Tn;               // 32768 rows

constexpr int NPROD = 24;                  // col-blocks per group
constexpr int NGRP  = 8;                   // batch groups (8 batches each)
constexpr int SLOTS = 4;                   // publish ring depth
constexpr int GSTR  = NPROD * 512;         // floats per group per slot
constexpr int SSTR  = NGRP * GSTR;         // floats per slot
constexpr int FSTR  = 32;                  // flag stride (ints) = 128B line
constexpr int PITCH = 792;                 // plane row pitch (ushorts), 768+24 pad
constexpr int PSZ   = 16 * PITCH;          // plane size (ushorts) = 12672

// workspace offsets (in floats)
constexpr size_t OFF_XP    = 0;
constexpr size_t OFF_H12   = OFF_XP  + (size_t)RTn * Hn;
constexpr size_t OFF_TAGX  = OFF_H12 + (size_t)RTn * Hn;
constexpr size_t OFF_C12   = OFF_TAGX + (size_t)RTn;
constexpr size_t OFF_PUB   = OFF_C12  + Hn;
constexpr size_t OFF_FLAGS = OFF_PUB  + (size_t)SLOTS * SSTR;  // int region

__device__ inline unsigned short f2bf(float f) {
    union { float f; unsigned u; } v{f};
    unsigned r = v.u + 0x7FFF + ((v.u >> 16) & 1);   // RNE
    return (unsigned short)(r >> 16);
}
__device__ inline float bf2f(unsigned short h) {
    union { unsigned u; float f; } v; v.u = ((unsigned)h) << 16; return v.f;
}

// ---------------------------------------------------------------------------
__global__ void __launch_bounds__(256) c12_kernel(const float* __restrict__ Whh12,
                                                  const float* __restrict__ hinit,
                                                  const float* __restrict__ b12,
                                                  float* __restrict__ c12) {
    int j = blockIdx.x * 256 + threadIdx.x;
    if (j >= Hn) return;
    float s = b12[j];
    const float* row = Whh12 + (size_t)j * Hn;
    for (int e = 0; e < Hn; ++e) s += row[e] * hinit[e];
    c12[j] = s;
}

// ---------------------------------------------------------------------------
__global__ void __launch_bounds__(256) tagx_kernel(const float* __restrict__ bert,
                                                   const float* __restrict__ Wtag,
                                                   const float* __restrict__ btag,
                                                   float* __restrict__ tagx) {
    int r = blockIdx.x * 4 + (threadIdx.x >> 6);
    int lane = threadIdx.x & 63;
    const float* wx = Wtag + 2 * Hn;
    const float* row = bert + (size_t)r * Hn;
    float s = 0.f;
    for (int e = lane; e < Hn; e += 64) s += row[e] * wx[e];
    #pragma unroll
    for (int m = 1; m < 64; m <<= 1) s += __shfl_xor(s, m, 64);
    if (lane == 0) tagx[r] = s + btag[0];
}

// ---------------------------------------------------------------------------
// Precompute GEMM (fp32): xp11 and tanh'ed h12_seq.
__global__ void __launch_bounds__(256) gemm_pre(const float* __restrict__ bert,
                                                const float* __restrict__ Wih11,
                                                const float* __restrict__ Wih12,
                                                const float* __restrict__ b11,
                                                const float* __restrict__ c12,
                                                float* __restrict__ xp,
                                                float* __restrict__ h12) {
    constexpr int BM = 128, BN = 64, BK = 16;
    __shared__ float As[BK][BM];
    __shared__ float Ws[BK][BN];
    const int bid = blockIdx.x;
    const int mt = bid / 24, nt = bid % 24;
    const int r0 = mt * BM;
    const int n0 = nt * BN;
    const bool second = (n0 >= Hn);
    const float* W = second ? Wih12 : Wih11;
    const int jbase = second ? (n0 - Hn) : n0;
    const int tid = threadIdx.x;
    const int ty = tid >> 4, tx = tid & 15;
    const int lrow = tid >> 1, lhalf = (tid & 1) * 8;
    const int wjl = tid & 63, wkk = tid >> 6;
    float acc[8][4] = {};
    for (int e0 = 0; e0 < Hn; e0 += BK) {
        float4 av0 = *(const float4*)(bert + (size_t)(r0 + lrow) * Hn + e0 + lhalf);
        float4 av1 = *(const float4*)(bert + (size_t)(r0 + lrow) * Hn + e0 + lhalf + 4);
        float4 wv  = *(const float4*)(W + (size_t)(jbase + wjl) * Hn + e0 + wkk * 4);
        As[lhalf + 0][lrow] = av0.x; As[lhalf + 1][lrow] = av0.y;
        As[lhalf + 2][lrow] = av0.z; As[lhalf + 3][lrow] = av0.w;
        As[lhalf + 4][lrow] = av1.x; As[lhalf + 5][lrow] = av1.y;
        As[lhalf + 6][lrow] = av1.z; As[lhalf + 7][lrow] = av1.w;
        Ws[wkk * 4 + 0][wjl] = wv.x; Ws[wkk * 4 + 1][wjl] = wv.y;
        Ws[wkk * 4 + 2][wjl] = wv.z; Ws[wkk * 4 + 3][wjl] = wv.w;
        __syncthreads();
        #pragma unroll
        for (int k = 0; k < BK; ++k) {
            float a[8], w[4];
            *(float4*)&a[0] = *(const float4*)&As[k][ty * 8];
            *(float4*)&a[4] = *(const float4*)&As[k][ty * 8 + 4];
            *(float4*)&w[0] = *(const float4*)&Ws[k][tx * 4];
            #pragma unroll
            for (int ii = 0; ii < 8; ++ii)
                #pragma unroll
                for (int jj = 0; jj < 4; ++jj)
                    acc[ii][jj] += a[ii] * w[jj];
        }
        __syncthreads();
    }
    #pragma unroll
    for (int ii = 0; ii < 8; ++ii) {
        size_t r = (size_t)(r0 + ty * 8 + ii);
        if (!second) {
            #pragma unroll
            for (int jj = 0; jj < 4; ++jj) {
                int n = n0 + tx * 4 + jj;
                xp[r * Hn + n] = acc[ii][jj] + b11[n];
            }
        } else {
            #pragma unroll
            for (int jj = 0; jj < 4; ++jj) {
                int n = n0 - Hn + tx * 4 + jj;
                h12[r * Hn + n] = tanhf(acc[ii][jj] + c12[n]);
            }
        }
    }
}

// ---------------------------------------------------------------------------
// Dataflow scan v5: R8 exchange + split-bf16 MFMA matvec.
// 192 blocks = 8 groups(8 batches) x 24 col-blocks(32 cols), 512 threads.
// Weights: 36 bf16 B-frags (hi/lo) = 144 VGPR, loop-invariant.
// State: published as packed (hi,lo) bf16 pairs (8B/thread); consumer
// scatters into [16][792] bf16 LDS planes (rows 8-15 zero). h2 carry fp32
// in registers; 3-term split product => ~1e-5 per-step matvec error.
__global__ void __launch_bounds__(512, 2) scan_kernel(
        const float* __restrict__ xp, const float* __restrict__ h12,
        const float* __restrict__ tagx,
        const float* __restrict__ Whh11, const float* __restrict__ Wih21,
        const float* __restrict__ Whh21, const float* __restrict__ b21,
        const float* __restrict__ Wtag,
        float* __restrict__ pub, int* __restrict__ flags,
        float* __restrict__ out) {
    __shared__ unsigned short planes[4 * PSZ];   // h1hi,h1lo,h2hi,h2lo  101.4 KB
    __shared__ float redbuf[8][4][64][4];        // 32 KB [wave][acc][lane][reg]
    __shared__ float wt1[Hn], wt2[Hn];           // 6 KB
    __shared__ float tagbuf[8];

    const int tid  = threadIdx.x;
    const int wv   = tid >> 6;          // wave 0..7
    const int lane = tid & 63;
    const int bid  = blockIdx.x;
    const int g    = bid & 7;           // group (XCD round-robin heuristic)
    const int prod = bid >> 3;          // col-block 0..23

    // ---- loop-invariant: B-fragments (hi/lo bf16), 36 frags = 144 VGPR ----
    // layout: B[k][n] for 16x16x32: lane holds col n=(lane&15), k=(lane>>4)*8+i
    short8v wb[3][3][2][2];             // [mat][ktl][nt][hi=0/lo=1]
    {
        const float* Wm0 = Whh11;
        const float* Wm1 = Wih21;
        const float* Wm2 = Whh21;
        #pragma unroll
        for (int mt = 0; mt < 3; ++mt) {
            const float* Wmat = (mt == 0) ? Wm0 : (mt == 1) ? Wm1 : Wm2;
            #pragma unroll
            for (int ktl = 0; ktl < 3; ++ktl) {
                #pragma unroll
                for (int nt = 0; nt < 2; ++nt) {
                    int gcol = prod * 32 + nt * 16 + (lane & 15);
                    int k0   = (wv * 3 + ktl) * 32 + (lane >> 4) * 8;
                    const float* p = Wmat + (size_t)gcol * Hn + k0;
                    float4 f0 = *(const float4*)p;
                    float4 f1 = *(const float4*)(p + 4);
                    float fv[8] = {f0.x, f0.y, f0.z, f0.w, f1.x, f1.y, f1.z, f1.w};
                    union { short8v v; unsigned short u[8]; } hi, lo;
                    #pragma unroll
                    for (int i = 0; i < 8; ++i) {
                        unsigned short h = f2bf(fv[i]);
                        hi.u[i] = h;
                        lo.u[i] = f2bf(fv[i] - bf2f(h));
                    }
                    wb[mt][ktl][nt][0] = hi.v;
                    wb[mt][ktl][nt][1] = lo.v;
                }
            }
        }
    }
    for (int i = tid; i < Hn; i += 512) { wt1[i] = Wtag[i]; wt2[i] = Wtag[Hn + i]; }
    const int ecol = prod * 32 + (tid & 31);     // epilogue col for tid<256
    const float bias21 = b21[ecol];

    // zero all planes once (rows 8-15 stay zero forever; rows 0-7 overwritten)
    for (int i = tid; i < 4 * PSZ / 2; i += 512) ((unsigned int*)planes)[i] = 0u;

    float* outO   = out;
    float* outH2  = out + RTn;
    float* outTag = out + RTn + (size_t)RTn * Hn;
    int* myflag = flags + (g * NPROD + prod) * FSTR;
    float h2c = 0.f;                    // fp32 carry (tid<256: batch tid>>5, col ecol)
    __syncthreads();

    for (int t = 0; t < Tn; ++t) {
        // flag-independent prefetch
        float xpv = 0.f, h12pv = 0.f, tgxv = 0.f;
        if (tid < 256) {
            int m = tid >> 5;
            size_t rr = (size_t)(g * 8 + m) * Tn + t;
            xpv   = xp  [rr * Hn + ecol];
            h12pv = h12 [rr * Hn + ecol];
            tgxv  = tagx[rr];
        }

        // spin: 24 parallel pollers
        if (tid < NPROD) {
            const int* f = flags + (g * NPROD + tid) * FSTR;
            while (__hip_atomic_load(f, __ATOMIC_RELAXED,
                                     __HIP_MEMORY_SCOPE_AGENT) < t)
                __builtin_amdgcn_s_sleep(2);
        }
        __syncthreads();   // A

        // bulk gather 48 KB as 12 x 8B/thread, then scatter bf16 to planes
        {
            const unsigned long long* pubc =
                (const unsigned long long*)(pub + (size_t)(t & 3) * SSTR + g * GSTR);
            unsigned long long v[12];
            #pragma unroll
            for (int i = 0; i < 12; ++i) {
                int idx = tid + i * 512;            // 0..6143
                v[i] = __hip_atomic_load(pubc + idx, __ATOMIC_RELAXED,
                                         __HIP_MEMORY_SCOPE_AGENT);
            }
            #pragma unroll
            for (int i = 0; i < 12; ++i) {
                int idx = tid + i * 512;
                int p = idx >> 8, rem = idx & 255;
                int m = rem >> 5, jc = rem & 31;
                int base = m * PITCH + p * 32 + jc;
                unsigned long long u = v[i];
                planes[0 * PSZ + base] = (unsigned short)(u & 0xFFFF);
                planes[1 * PSZ + base] = (unsigned short)((u >> 16) & 0xFFFF);
                planes[2 * PSZ + base] = (unsigned short)((u >> 32) & 0xFFFF);
                planes[3 * PSZ + base] = (unsigned short)(u >> 48);
            }
        }
        __syncthreads();   // B: planes staged

        // gate: wave wv = batch wv; lane covers k = lane*12 .. +12
        {
            const int kb = lane * 12;
            float s = 0.f;
            #pragma unroll
            for (int part = 0; part < 3; ++part) {
                int off = wv * PITCH + kb + part * 4;
                unsigned long long u1h = *(const unsigned long long*)&planes[0 * PSZ + off];
                unsigned long long u1l = *(const unsigned long long*)&planes[1 * PSZ + off];
                unsigned long long u2h = *(const unsigned long long*)&planes[2 * PSZ + off];
                unsigned long long u2l = *(const unsigned long long*)&planes[3 * PSZ + off];
                #pragma unroll
                for (int e = 0; e < 4; ++e) {
                    int k = kb + part * 4 + e;
                    float h1 = bf2f((unsigned short)(u1h >> (16 * e)))
                             + bf2f((unsigned short)(u1l >> (16 * e)));
                    float h2 = bf2f((unsigned short)(u2h >> (16 * e)))
                             + bf2f((unsigned short)(u2l >> (16 * e)));
                    s = fmaf(h1, wt1[k], s);
                    s = fmaf(h2, wt2[k], s);
                }
            }
            #pragma unroll
            for (int mm = 1; mm < 64; mm <<= 1) s += __shfl_xor(s, mm, 64);
            if (lane == 0) tagbuf[wv] = s;
        }

        // MFMA matvec: wave wv covers K-tiles wv*3..+3 (k = cols of h)
        {
            f32x4 a00 = {0.f,0.f,0.f,0.f}, a01 = {0.f,0.f,0.f,0.f};   // f11 nt0,nt1
            f32x4 a10 = {0.f,0.f,0.f,0.f}, a11v = {0.f,0.f,0.f,0.f}; // f21 nt0,nt1
            const int ar = (lane & 15) * PITCH + (lane >> 4) * 8;
            #pragma unroll
            for (int ktl = 0; ktl < 3; ++ktl) {
                const int ko = (wv * 3 + ktl) * 32 + ar;
                short8v h1h = __builtin_bit_cast(short8v, *(const uint4*)&planes[0 * PSZ + ko]);
                short8v h1l = __builtin_bit_cast(short8v, *(const uint4*)&planes[1 * PSZ + ko]);
                short8v h2h = __builtin_bit_cast(short8v, *(const uint4*)&planes[2 * PSZ + ko]);
                short8v h2l = __builtin_bit_cast(short8v, *(const uint4*)&planes[3 * PSZ + ko]);
                // f11 = W11 . h1   (3-term split)
                a00 = __builtin_amdgcn_mfma_f32_16x16x32_bf16(h1h, wb[0][ktl][0][0], a00, 0, 0, 0);
                a00 = __builtin_amdgcn_mfma_f32_16x16x32_bf16(h1l, wb[0][ktl][0][0], a00, 0, 0, 0);
                a00 = __builtin_amdgcn_mfma_f32_16x16x32_bf16(h1h, wb[0][ktl][0][1], a00, 0, 0, 0);
                a01 = __builtin_amdgcn_mfma_f32_16x16x32_bf16(h1h, wb[0][ktl][1][0], a01, 0, 0, 0);
                a01 = __builtin_amdgcn_mfma_f32_16x16x32_bf16(h1l, wb[0][ktl][1][0], a01, 0, 0, 0);
                a01 = __builtin_amdgcn_mfma_f32_16x16x32_bf16(h1h, wb[0][ktl][1][1], a01, 0, 0, 0);
                // f21 = W21 . h1 + W2h . h2
                a10 = __builtin_amdgcn_mfma_f32_16x16x32_bf16(h1h, wb[1][ktl][0][0], a10, 0, 0, 0);
                a10 = __builtin_amdgcn_mfma_f32_16x16x32_bf16(h1l, wb[1][ktl][0][0], a10, 0, 0, 0);
                a10 = __builtin_amdgcn_mfma_f32_16x16x32_bf16(h1h, wb[1][ktl][0][1], a10, 0, 0, 0);
                a11v = __builtin_amdgcn_mfma_f32_16x16x32_bf16(h1h, wb[1][ktl][1][0], a11v, 0, 0, 0);
                a11v = __builtin_amdgcn_mfma_f32_16x16x32_bf16(h1l, wb[1][ktl][1][0], a11v, 0, 0, 0);
                a11v = __builtin_amdgcn_mfma_f32_16x16x32_bf16(h1h, wb[1][ktl][1][1], a11v, 0, 0, 0);
                a10 = __builtin_amdgcn_mfma_f32_16x16x32_bf16(h2h, wb[2][ktl][0][0], a10, 0, 0, 0);
                a10 = __builtin_amdgcn_mfma_f32_16x16x32_bf16(h2l, wb[2][ktl][0][0], a10, 0, 0, 0);
                a10 = __builtin_amdgcn_mfma_f32_16x16x32_bf16(h2h, wb[2][ktl][0][1], a10, 0, 0, 0);
                a11v = __builtin_amdgcn_mfma_f32_16x16x32_bf16(h2h, wb[2][ktl][1][0], a11v, 0, 0, 0);
                a11v = __builtin_amdgcn_mfma_f32_16x16x32_bf16(h2l, wb[2][ktl][1][0], a11v, 0, 0, 0);
                a11v = __builtin_amdgcn_mfma_f32_16x16x32_bf16(h2h, wb[2][ktl][1][1], a11v, 0, 0, 0);
            }
            *(f32x4*)&redbuf[wv][0][lane][0] = a00;
            *(f32x4*)&redbuf[wv][1][lane][0] = a01;
            *(f32x4*)&redbuf[wv][2][lane][0] = a10;
            *(f32x4*)&redbuf[wv][3][lane][0] = a11v;
        }
        __syncthreads();   // C: redbuf + tagbuf ready

        // epilogue: tid<256 = (batch m, col jc); D mapping: col=lane&15,
        // row=(lane>>4)*4+reg  =>  lane=(m>>2)*16+n, reg=m&3
        float o = 0.f, tg = 0.f, h2nv = 0.f;
        if (tid < 256) {
            int m = tid >> 5, jc = tid & 31;
            int n = jc & 15, nt = jc >> 4;
            int rl = (m >> 2) * 16 + n, rg = m & 3;
            float f11 = 0.f, f21 = 0.f;
            #pragma unroll
            for (int w = 0; w < 8; ++w) {
                f11 += redbuf[w][nt][rl][rg];
                f21 += redbuf[w][2 + nt][rl][rg];
            }
            tg = tagbuf[m] + tgxv;
            o  = 1.f / (1.f + expf(-tg));
            float h11v = tanhf(xpv + f11);
            float h21v = tanhf(f21 + bias21);
            float h1nv = h11v * (1.f - o) + h12pv * o;
            h2nv = h2c * (1.f - o) + h21v * o;
            h2c = h2nv;
            // split to (hi,lo) bf16 and publish packed 8B
            unsigned short h1h = f2bf(h1nv);
            unsigned short h1l = f2bf(h1nv - bf2f(h1h));
            unsigned short h2h = f2bf(h2nv);
            unsigned short h2l = f2bf(h2nv - bf2f(h2h));
            unsigned long long u = (unsigned long long)h1h
                                 | ((unsigned long long)h1l << 16)
                                 | ((unsigned long long)h2h << 32)
                                 | ((unsigned long long)h2l << 48);
            unsigned long long* pn =
                (unsigned long long*)(pub + (size_t)((t + 1) & 3) * SSTR + g * GSTR)
                + prod * 256 + m * 32 + jc;
            __hip_atomic_store(pn, u, __ATOMIC_RELAXED, __HIP_MEMORY_SCOPE_AGENT);
        }
        __syncthreads();   // D: vmcnt(0) drains publish stores
        if (tid == 0)
            __hip_atomic_store(myflag, t + 1, __ATOMIC_RELAXED,
                               __HIP_MEMORY_SCOPE_AGENT);
        // outputs after the flag — off the inter-block critical chain
        if (tid < 256) {
            int m = tid >> 5;
            size_t rr = (size_t)(g * 8 + m) * Tn + t;
            outH2[rr * Hn + ecol] = h2nv;
            if ((tid & 31) == 0 && prod == 0) { outO[rr] = o; outTag[rr] = tg; }
        }
    }
}

// ---------------------------------------------------------------------------
extern "C" void kernel_launch(void* const* d_in, const int* in_sizes, int n_in,
                              void* d_out, int out_size, void* d_ws, size_t ws_size,
                              hipStream_t stream) {
    const float* bert  = (const float*)d_in[0];
    const float* Wih11 = (const float*)d_in[1];
    const float* Whh11 = (const float*)d_in[2];
    const float* b11   = (const float*)d_in[3];
    const float* Wih12 = (const float*)d_in[4];
    const float* Whh12 = (const float*)d_in[5];
    const float* b12   = (const float*)d_in[6];
    const float* Wih21 = (const float*)d_in[7];
    const float* Whh21 = (const float*)d_in[8];
    const float* b21   = (const float*)d_in[9];
    const float* Wtag  = (const float*)d_in[10];
    const float* btag  = (const float*)d_in[11];
    const float* hinit = (const float*)d_in[12];
    float* ws = (float*)d_ws;
    float* xp    = ws + OFF_XP;
    float* h12   = ws + OFF_H12;
    float* tagx  = ws + OFF_TAGX;
    float* c12   = ws + OFF_C12;
    float* pub   = ws + OFF_PUB;
    int*   flags = (int*)(ws + OFF_FLAGS);
    float* out   = (float*)d_out;

    // zero publish ring (slot 0 = initial h=0 state: bf16 zeros) and flags
    hipMemsetAsync(pub,   0, (size_t)SLOTS * SSTR * sizeof(float), stream);
    hipMemsetAsync(flags, 0, NGRP * NPROD * FSTR * sizeof(int), stream);

    c12_kernel<<<3, 256, 0, stream>>>(Whh12, hinit, b12, c12);
    gemm_pre<<<256 * 24, 256, 0, stream>>>(bert, Wih11, Wih12, b11, c12, xp, h12);
    tagx_kernel<<<RTn / 4, 256, 0, stream>>>(bert, Wtag, btag, tagx);

    void* params[] = { &xp, &h12, &tagx, &Whh11, &Wih21, &Whh21, &b21, &Wtag,
                       &pub, &flags, &out };
    hipLaunchCooperativeKernel((void*)scan_kernel, dim3(192), dim3(512),
                               params, 0, stream);
}